// Round 16
// baseline (172.038 us; speedup 1.0000x reference)
//
#include <hip/hip_runtime.h>
#include <cstdint>
#include <cstddef>

#define B 4
#define N 16
#define V 32
#define HW 25600
#define TOPK 7
#define NSLB 5      // kTop slabs of 5120 px per bn (320 items)
#define NCA 200     // kA chunks of 128 px (800 items)
#define NCC 400     // kC chunks of 64 px (1600 items)

__device__ __forceinline__ bool better(float av, int ai, float bv, int bi) {
    return (av > bv) || (av == bv && ai < bi);
}

// ================= phase bodies =================

__device__ __forceinline__ void kTop_body(
    int slab, int tid,
    const float* __restrict__ pred, const float* __restrict__ gt,
    float* __restrict__ cand_val, int* __restrict__ cand_idx,
    float* __restrict__ cnt_part,
    float* rwv, int* rwi, float* csum) {
    int bn = slab / NSLB, sl = slab % NSLB;
    int b = bn >> 4;
    int lane = tid & 63, wave = tid >> 6;
    int base = sl * 5120;

    const float* gtrow = gt + (size_t)bn * HW + base;
    const float* pr = pred + (size_t)b * HW + base;

    float tv[TOPK]; int ti[TOPK];
#pragma unroll
    for (int j = 0; j < TOPK; ++j) { tv[j] = -INFINITY; ti[j] = 0x7fffffff; }
    float cnt = 0.f;

#pragma unroll
    for (int it = 0; it < 5; ++it) {
        int p = it * 1024 + tid * 4;
        float4 g4 = *reinterpret_cast<const float4*>(gtrow + p);
        float4 p4 = *reinterpret_cast<const float4*>(pr + p);
        cnt += g4.x + g4.y + g4.z + g4.w;
        float ca[4] = { p4.x * g4.x, p4.y * g4.y, p4.z * g4.z, p4.w * g4.w };
#pragma unroll
        for (int j = 0; j < 4; ++j) {
            float c = ca[j]; int pi = base + p + j;
            if (better(c, pi, tv[TOPK - 1], ti[TOPK - 1])) {
                tv[TOPK - 1] = c; ti[TOPK - 1] = pi;
#pragma unroll
                for (int q = TOPK - 2; q >= 0; --q) {
                    if (better(tv[q + 1], ti[q + 1], tv[q], ti[q])) {
                        float fv = tv[q]; int fi = ti[q];
                        tv[q] = tv[q + 1]; ti[q] = ti[q + 1];
                        tv[q + 1] = fv; ti[q + 1] = fi;
                    }
                }
            }
        }
    }

#pragma unroll
    for (int off = 32; off > 0; off >>= 1) cnt += __shfl_down(cnt, off);
    if (lane == 0) csum[wave] = cnt;
    __syncthreads();
    if (tid == 0) cnt_part[slab] = csum[0] + csum[1] + csum[2] + csum[3];

    int cbase = slab * TOPK;
    for (int r = 0; r < TOPK; ++r) {
        float bv = tv[0]; int bi = ti[0];
#pragma unroll
        for (int m = 1; m <= 32; m <<= 1) {
            float ov = __shfl_xor(bv, m);
            int oi = __shfl_xor(bi, m);
            if (better(ov, oi, bv, bi)) { bv = ov; bi = oi; }
        }
        if (lane == 0) { rwv[wave] = bv; rwi[wave] = bi; }
        __syncthreads();
        float fv = rwv[0]; int fi = rwi[0];
#pragma unroll
        for (int w = 1; w < 4; ++w)
            if (better(rwv[w], rwi[w], fv, fi)) { fv = rwv[w]; fi = rwi[w]; }
        if (ti[0] == fi) {
#pragma unroll
            for (int q = 0; q < TOPK - 1; ++q) { tv[q] = tv[q + 1]; ti[q] = ti[q + 1]; }
            tv[TOPK - 1] = -INFINITY; ti[TOPK - 1] = 0x7fffffff;
        }
        if (tid == 0) { cand_val[cbase + r] = fv; cand_idx[cbase + r] = fi; }
        __syncthreads();
    }
}

// kA with gt staged in LDS (g-loads were 8x redundant at global issue level)
__device__ __forceinline__ void kA_body(
    int w, int tid,
    const float* __restrict__ feat, const float* __restrict__ gt,
    float* __restrict__ ms_part, float* __restrict__ s2_part,
    float (*g_lds)[132]) {
    int xcd = w & 7;
    int b = xcd >> 1;
    int ch = (w >> 3) * 2 + (xcd & 1);
    int c0 = ch * 128;
    int ng = tid >> 6, vg = (tid >> 3) & 7, pg = tid & 7;

    {   // stage gt tile 16 x 128, coalesced float4
        const float* gb0 = gt + (size_t)(b * N) * HW + c0;
#pragma unroll
        for (int k = 0; k < 2; ++k) {
            int u = tid + 256 * k;
            int row = u >> 5, p4 = (u & 31) * 4;
            *reinterpret_cast<float4*>(&g_lds[row][p4]) =
                *reinterpret_cast<const float4*>(gb0 + (size_t)row * HW + p4);
        }
    }
    __syncthreads();

    const float* fb = feat + (size_t)(b * V + vg * 4) * HW + c0 + pg * 4;

    float acc[4][4];
#pragma unroll
    for (int i = 0; i < 4; ++i)
#pragma unroll
        for (int j = 0; j < 4; ++j) acc[i][j] = 0.f;
    float s2a[4] = { 0.f, 0.f, 0.f, 0.f };

#pragma unroll
    for (int q = 0; q < 4; ++q) {
        int p = q * 32 + pg * 4;
        float4 g4[4], f4[4];
#pragma unroll
        for (int i = 0; i < 4; ++i)
            g4[i] = *reinterpret_cast<const float4*>(&g_lds[ng * 4 + i][p]);
#pragma unroll
        for (int j = 0; j < 4; ++j)
            f4[j] = *reinterpret_cast<const float4*>(fb + (size_t)j * HW + q * 32);
        float ffx = 0.f, ffy = 0.f, ffz = 0.f, ffw = 0.f;
#pragma unroll
        for (int j = 0; j < 4; ++j) {
            ffx = fmaf(f4[j].x, f4[j].x, ffx);
            ffy = fmaf(f4[j].y, f4[j].y, ffy);
            ffz = fmaf(f4[j].z, f4[j].z, ffz);
            ffw = fmaf(f4[j].w, f4[j].w, ffw);
        }
#pragma unroll
        for (int i = 0; i < 4; ++i) {
#pragma unroll
            for (int j = 0; j < 4; ++j) {
                acc[i][j] = fmaf(g4[i].x, f4[j].x, acc[i][j]);
                acc[i][j] = fmaf(g4[i].y, f4[j].y, acc[i][j]);
                acc[i][j] = fmaf(g4[i].z, f4[j].z, acc[i][j]);
                acc[i][j] = fmaf(g4[i].w, f4[j].w, acc[i][j]);
            }
            s2a[i] = fmaf(g4[i].x, ffx, s2a[i]);
            s2a[i] = fmaf(g4[i].y, ffy, s2a[i]);
            s2a[i] = fmaf(g4[i].z, ffz, s2a[i]);
            s2a[i] = fmaf(g4[i].w, ffw, s2a[i]);
        }
    }
#pragma unroll
    for (int m = 1; m <= 4; m <<= 1)
#pragma unroll
        for (int i = 0; i < 4; ++i)
#pragma unroll
            for (int j = 0; j < 4; ++j) acc[i][j] += __shfl_xor(acc[i][j], m);
    size_t blk = (size_t)(b * NCA + ch);
    if (pg == 0) {
        float* dst = ms_part + blk * 512;
#pragma unroll
        for (int i = 0; i < 4; ++i)
#pragma unroll
            for (int j = 0; j < 4; ++j)
                dst[(ng * 4 + i) * 32 + vg * 4 + j] = acc[i][j];
    }
#pragma unroll
    for (int m = 1; m <= 32; m <<= 1)
#pragma unroll
        for (int i = 0; i < 4; ++i) s2a[i] += __shfl_xor(s2a[i], m);
    if ((tid & 63) == 0) {
#pragma unroll
        for (int i = 0; i < 4; ++i)
            s2_part[blk * 16 + ng * 4 + i] = s2a[i];
    }
}

// ---------------- kAT: kA chunks (0..799) + kTop slabs (800..1119) ----------------
__global__ __launch_bounds__(256) void kAT(
    const float* __restrict__ pred, const float* __restrict__ feat,
    const float* __restrict__ gt,
    float* __restrict__ ms_part, float* __restrict__ s2_part,
    float* __restrict__ cand_val, int* __restrict__ cand_idx,
    float* __restrict__ cnt_part, float* __restrict__ out,
    int* __restrict__ done_cnt) {
    __shared__ float g_lds[16][132];
    __shared__ float rwv[4]; __shared__ int rwi[4]; __shared__ float csum[4];
    int s = blockIdx.x;
    int tid = threadIdx.x;
    if (s == 0) {
        if (tid == 0) { out[0] = 0.f; out[1] = 0.f; out[2] = 0.f; }
        if (tid < 4) done_cnt[tid] = 0;
    }
    if (s < 800) kA_body(s, tid, feat, gt, ms_part, s2_part, g_lds);
    else kTop_body(s - 800, tid, pred, gt, cand_val, cand_idx, cnt_part,
                   rwv, rwi, csum);
}

// ---------------- kB: block-wide reduces + 35-candidate merge + mu/E/l2 ----------------
__global__ __launch_bounds__(256) void kB(
    const float* __restrict__ feat, const float* __restrict__ ms_part,
    const float* __restrict__ s2_part,
    const float* __restrict__ cand_val, const int* __restrict__ cand_idx,
    const float* __restrict__ cnt_part, const int* __restrict__ valid,
    float* __restrict__ Ebuf, float* __restrict__ cntbuf, float* __restrict__ out) {
    int bn = blockIdx.x;
    int b = bn >> 4, n = bn & 15;
    int tid = threadIdx.x;
    int lane = tid & 63, wave = tid >> 6;

    __shared__ float msl[8][33];
    __shared__ float s2w[4];
    __shared__ int idx7[TOPK];

    {
        int sl = tid >> 5, v = tid & 31;
        const float* src = ms_part + ((size_t)(b * NCA) + sl) * 512 + n * 32 + v;
        float sm = 0.f;
#pragma unroll 5
        for (int k = 0; k < 25; ++k) sm += src[(size_t)(8 * k) * 512];
        msl[sl][v] = sm;
    }
    {
        float s2v = 0.f;
        if (tid < NCA) s2v = s2_part[((size_t)(b * NCA) + tid) * 16 + n];
#pragma unroll
        for (int m = 1; m <= 32; m <<= 1) s2v += __shfl_xor(s2v, m);
        if (lane == 0) s2w[wave] = s2v;
    }
    if (wave == 0) {
        float cv = -INFINITY; int ci = 0x7fffffff;
        if (lane < NSLB * TOPK) {
            cv = cand_val[(size_t)bn * NSLB * TOPK + lane];
            ci = cand_idx[(size_t)bn * NSLB * TOPK + lane];
        }
#pragma unroll
        for (int r = 0; r < TOPK; ++r) {
            float bv = cv; int bi = ci;
#pragma unroll
            for (int m = 1; m <= 32; m <<= 1) {
                float ov = __shfl_xor(bv, m);
                int oi = __shfl_xor(bi, m);
                if (better(ov, oi, bv, bi)) { bv = ov; bi = oi; }
            }
            if (ci == bi) { cv = -INFINITY; ci = 0x7fffffff; }
            if (lane == 0) idx7[r] = bi;
        }
    }
    __syncthreads();

    if (tid < 32) {
        const float* cp = cnt_part + bn * NSLB;
        float cnt = cp[0] + cp[1] + cp[2] + cp[3] + cp[4];
        float msum = msl[0][tid] + msl[1][tid] + msl[2][tid] + msl[3][tid]
                   + msl[4][tid] + msl[5][tid] + msl[6][tid] + msl[7][tid];
        float pix = fmaxf(cnt, 1.0f);
        float mu = msum / pix;
        Ebuf[(size_t)bn * 256 + tid] = mu;
        float msq = mu * mu;
#pragma unroll
        for (int m = 1; m <= 16; m <<= 1) msq += __shfl_xor(msq, m);
        if (tid == 0) {
            cntbuf[bn] = cnt;
            float s2 = s2w[0] + s2w[1] + s2w[2] + s2w[3];
            atomicAdd(out + 2, (s2 / pix - msq) * (float)valid[bn]);
        }
    } else {
        int t = tid - 32;
        if (t < 224) {
            int r = t >> 5, v = t & 31;
            Ebuf[(size_t)bn * 256 + (r + 1) * 32 + v] =
                feat[((size_t)b * V + v) * HW + idx7[r]];
        }
    }
}

// ---------------- kCD: dice partials (LDS-staged) + last-block-per-b fold ----------------
__global__ __launch_bounds__(256) void kCD(
    const float* __restrict__ feat, const float* __restrict__ gt,
    const float* __restrict__ Ebuf, float* __restrict__ sums_part,
    const float* __restrict__ cntbuf, const int* __restrict__ valid,
    float* __restrict__ out, int* __restrict__ done_cnt) {
    int s = blockIdx.x;                 // 1600
    int xcd = s & 7;
    int b = xcd >> 1;
    int ch = (s >> 3) * 2 + (xcd & 1);  // 0..399
    int c0 = ch * 64;
    int tid = threadIdx.x;
    int n = tid >> 4, pg = tid & 15;

    __shared__ __attribute__((aligned(16))) float f_lds[32][64];
    __shared__ float e_lds[8 * 16 * 36];
    __shared__ float red[16][17];
    __shared__ int lastflag;
    __shared__ float fin2[16][17];

    const float* eb = Ebuf + (size_t)b * 4096;
#pragma unroll
    for (int k = 0; k < 4; ++k) {
        int q = (tid + 256 * k) * 4;
        int nn = q >> 8, rr = (q >> 5) & 7, vv = q & 31;
        *reinterpret_cast<float4*>(&e_lds[(rr * 16 + nn) * 36 + vv]) =
            *reinterpret_cast<const float4*>(eb + q);
    }
    {
        const float* fb0 = feat + (size_t)b * V * HW + c0;
#pragma unroll
        for (int k = 0; k < 2; ++k) {
            int u = tid + 256 * k;
            int v = u >> 4, p4 = (u & 15) * 4;
            *reinterpret_cast<float4*>(&f_lds[v][p4]) =
                *reinterpret_cast<const float4*>(fb0 + (size_t)v * HW + p4);
        }
    }
    __syncthreads();

    float4 g4 = *reinterpret_cast<const float4*>(gt + (size_t)(b * N + n) * HW + c0 + pg * 4);

    float acc[8][4];
#pragma unroll
    for (int r = 0; r < 8; ++r)
#pragma unroll
        for (int j = 0; j < 4; ++j) acc[r][j] = 0.f;

#pragma unroll
    for (int vq = 0; vq < 8; ++vq) {
        float4 f0 = *reinterpret_cast<const float4*>(&f_lds[vq * 4 + 0][pg * 4]);
        float4 f1 = *reinterpret_cast<const float4*>(&f_lds[vq * 4 + 1][pg * 4]);
        float4 f2 = *reinterpret_cast<const float4*>(&f_lds[vq * 4 + 2][pg * 4]);
        float4 f3 = *reinterpret_cast<const float4*>(&f_lds[vq * 4 + 3][pg * 4]);
#pragma unroll
        for (int r = 0; r < 8; ++r) {
            float4 e4 = *reinterpret_cast<const float4*>(&e_lds[(r * 16 + n) * 36 + vq * 4]);
            acc[r][0] = fmaf(e4.x, f0.x, acc[r][0]);
            acc[r][0] = fmaf(e4.y, f1.x, acc[r][0]);
            acc[r][0] = fmaf(e4.z, f2.x, acc[r][0]);
            acc[r][0] = fmaf(e4.w, f3.x, acc[r][0]);
            acc[r][1] = fmaf(e4.x, f0.y, acc[r][1]);
            acc[r][1] = fmaf(e4.y, f1.y, acc[r][1]);
            acc[r][1] = fmaf(e4.z, f2.y, acc[r][1]);
            acc[r][1] = fmaf(e4.w, f3.y, acc[r][1]);
            acc[r][2] = fmaf(e4.x, f0.z, acc[r][2]);
            acc[r][2] = fmaf(e4.y, f1.z, acc[r][2]);
            acc[r][2] = fmaf(e4.z, f2.z, acc[r][2]);
            acc[r][2] = fmaf(e4.w, f3.z, acc[r][2]);
            acc[r][3] = fmaf(e4.x, f0.w, acc[r][3]);
            acc[r][3] = fmaf(e4.y, f1.w, acc[r][3]);
            acc[r][3] = fmaf(e4.z, f2.w, acc[r][3]);
            acc[r][3] = fmaf(e4.w, f3.w, acc[r][3]);
        }
    }

    float p2[8], tp[8];
#pragma unroll
    for (int r = 0; r < 8; ++r) { p2[r] = 0.f; tp[r] = 0.f; }
    float ga[4] = { g4.x, g4.y, g4.z, g4.w };
#pragma unroll
    for (int r = 0; r < 8; ++r)
#pragma unroll
        for (int j = 0; j < 4; ++j) {
            float sg = 1.f / (1.f + __expf(-acc[r][j]));
            p2[r] = fmaf(sg, sg, p2[r]);
            tp[r] = fmaf(ga[j], sg, tp[r]);
        }
#pragma unroll
    for (int m = 1; m <= 8; m <<= 1)
#pragma unroll
        for (int r = 0; r < 8; ++r) {
            p2[r] += __shfl_xor(p2[r], m);
            tp[r] += __shfl_xor(tp[r], m);
        }
    if (pg == 0) {
#pragma unroll
        for (int r = 0; r < 8; ++r) {
            red[n][r * 2] = p2[r];
            red[n][r * 2 + 1] = tp[r];
        }
    }
    __syncthreads();
    sums_part[(size_t)(b * NCC + ch) * 256 + tid] = red[tid >> 4][tid & 15];

    // ---- last-block-per-b dice fold (replaces the kD kernel) ----
    __threadfence();                            // release our sums_part stores
    if (tid == 0) {
        int old = atomicAdd(&done_cnt[b], 1);   // device-scope ticket
        lastflag = (old == NCC - 1);
    }
    __syncthreads();
    if (!lastflag) return;
    __threadfence();                            // acquire others' stores

    {
        int slot = tid & 15;                    // n = tid>>4 (reuse)
        float sv = 0.f;
        const float* src = sums_part + (size_t)b * NCC * 256 + n * 16 + slot;
#pragma unroll 8
        for (int k = 0; k < NCC; ++k) sv += src[(size_t)k * 256];
        fin2[n][slot] = sv;
    }
    __syncthreads();
    if (tid < 16) {
        int bn = b * 16 + tid;
        float vw = (float)valid[bn];
        float cnt = cntbuf[bn];
        float mloss = 0.f, iloss = 0.f;
#pragma unroll
        for (int r = 0; r < 8; ++r) {
            float pp = fin2[tid][r * 2];
            float tt = fin2[tid][r * 2 + 1];
            float denom = fmaxf(pp + cnt, 1e-8f);
            float dice = 1.f - 2.f * tt / denom;
            if (r == 0) mloss = dice * vw;
            else iloss += dice * vw;
        }
        atomicAdd(out + 0, mloss);
        atomicAdd(out + 1, iloss);
    }
}

extern "C" void kernel_launch(void* const* d_in, const int* in_sizes, int n_in,
                              void* d_out, int out_size, void* d_ws, size_t ws_size,
                              hipStream_t stream) {
    const float* pred = (const float*)d_in[0];
    const float* feat = (const float*)d_in[1];
    const float* gtin = (const float*)d_in[2];
    const int* valid  = (const int*)d_in[3];
    float* out = (float*)d_out;

    char* ws = (char*)d_ws;
    float* ms_part   = (float*)(ws);                 // 800*512*4   = 1,638,400
    float* s2_part   = (float*)(ws + 1638400);       // 800*16*4    =    51,200
    float* cand_val  = (float*)(ws + 1689600);       // 320*7*4     =     8,960
    int*   cand_idx  = (int*)  (ws + 1698560);       //                   8,960
    float* cnt_part  = (float*)(ws + 1707520);       // 320*4       =     1,280
    float* sums_part = (float*)(ws + 1708800);       // 1600*256*4  = 1,638,400
    float* Ebuf      = (float*)(ws + 3347200);       // 64*256*4    =    65,536
    float* cntbuf    = (float*)(ws + 3412736);       // 256
    int*   done_cnt  = (int*)  (ws + 3412992);       // 16

    kAT<<<800 + B * N * NSLB, 256, 0, stream>>>(pred, feat, gtin, ms_part, s2_part,
                                                cand_val, cand_idx, cnt_part, out,
                                                done_cnt);
    kB<<<B * N, 256, 0, stream>>>(feat, ms_part, s2_part, cand_val, cand_idx,
                                  cnt_part, valid, Ebuf, cntbuf, out);
    kCD<<<B * NCC, 256, 0, stream>>>(feat, gtin, Ebuf, sums_part, cntbuf, valid,
                                     out, done_cnt);
}

// Round 17
// 59.959 us; speedup vs baseline: 2.8693x; 2.8693x over previous
//
#include <hip/hip_runtime.h>
#include <cstdint>
#include <cstddef>

#define B 4
#define N 16
#define V 32
#define HW 25600
#define TOPK 7
#define NSLB 5      // kTop slabs of 5120 px per bn (320 items)
#define NCA 200     // kA chunks of 128 px (800 items)
#define NCC 400     // kC chunks of 64 px (1600 items)

__device__ __forceinline__ bool better(float av, int ai, float bv, int bi) {
    return (av > bv) || (av == bv && ai < bi);
}

// ================= phase bodies =================

__device__ __forceinline__ void kTop_body(
    int slab, int tid,
    const float* __restrict__ pred, const float* __restrict__ gt,
    float* __restrict__ cand_val, int* __restrict__ cand_idx,
    float* __restrict__ cnt_part,
    float* rwv, int* rwi, float* csum) {
    int bn = slab / NSLB, sl = slab % NSLB;
    int b = bn >> 4;
    int lane = tid & 63, wave = tid >> 6;
    int base = sl * 5120;

    const float* gtrow = gt + (size_t)bn * HW + base;
    const float* pr = pred + (size_t)b * HW + base;

    float tv[TOPK]; int ti[TOPK];
#pragma unroll
    for (int j = 0; j < TOPK; ++j) { tv[j] = -INFINITY; ti[j] = 0x7fffffff; }
    float cnt = 0.f;

#pragma unroll
    for (int it = 0; it < 5; ++it) {
        int p = it * 1024 + tid * 4;
        float4 g4 = *reinterpret_cast<const float4*>(gtrow + p);
        float4 p4 = *reinterpret_cast<const float4*>(pr + p);
        cnt += g4.x + g4.y + g4.z + g4.w;
        float ca[4] = { p4.x * g4.x, p4.y * g4.y, p4.z * g4.z, p4.w * g4.w };
#pragma unroll
        for (int j = 0; j < 4; ++j) {
            float c = ca[j]; int pi = base + p + j;
            if (better(c, pi, tv[TOPK - 1], ti[TOPK - 1])) {
                tv[TOPK - 1] = c; ti[TOPK - 1] = pi;
#pragma unroll
                for (int q = TOPK - 2; q >= 0; --q) {
                    if (better(tv[q + 1], ti[q + 1], tv[q], ti[q])) {
                        float fv = tv[q]; int fi = ti[q];
                        tv[q] = tv[q + 1]; ti[q] = ti[q + 1];
                        tv[q + 1] = fv; ti[q + 1] = fi;
                    }
                }
            }
        }
    }

#pragma unroll
    for (int off = 32; off > 0; off >>= 1) cnt += __shfl_down(cnt, off);
    if (lane == 0) csum[wave] = cnt;
    __syncthreads();
    if (tid == 0) cnt_part[slab] = csum[0] + csum[1] + csum[2] + csum[3];

    int cbase = slab * TOPK;
    for (int r = 0; r < TOPK; ++r) {
        float bv = tv[0]; int bi = ti[0];
#pragma unroll
        for (int m = 1; m <= 32; m <<= 1) {
            float ov = __shfl_xor(bv, m);
            int oi = __shfl_xor(bi, m);
            if (better(ov, oi, bv, bi)) { bv = ov; bi = oi; }
        }
        if (lane == 0) { rwv[wave] = bv; rwi[wave] = bi; }
        __syncthreads();
        float fv = rwv[0]; int fi = rwi[0];
#pragma unroll
        for (int w = 1; w < 4; ++w)
            if (better(rwv[w], rwi[w], fv, fi)) { fv = rwv[w]; fi = rwi[w]; }
        if (ti[0] == fi) {
#pragma unroll
            for (int q = 0; q < TOPK - 1; ++q) { tv[q] = tv[q + 1]; ti[q] = ti[q + 1]; }
            tv[TOPK - 1] = -INFINITY; ti[TOPK - 1] = 0x7fffffff;
        }
        if (tid == 0) { cand_val[cbase + r] = fv; cand_idx[cbase + r] = fi; }
        __syncthreads();
    }
}

// kA with gt staged in LDS (g-loads were 8x redundant at global issue level)
__device__ __forceinline__ void kA_body(
    int w, int tid,
    const float* __restrict__ feat, const float* __restrict__ gt,
    float* __restrict__ ms_part, float* __restrict__ s2_part,
    float (*g_lds)[132]) {
    int xcd = w & 7;
    int b = xcd >> 1;
    int ch = (w >> 3) * 2 + (xcd & 1);
    int c0 = ch * 128;
    int ng = tid >> 6, vg = (tid >> 3) & 7, pg = tid & 7;

    {   // stage gt tile 16 x 128, coalesced float4
        const float* gb0 = gt + (size_t)(b * N) * HW + c0;
#pragma unroll
        for (int k = 0; k < 2; ++k) {
            int u = tid + 256 * k;
            int row = u >> 5, p4 = (u & 31) * 4;
            *reinterpret_cast<float4*>(&g_lds[row][p4]) =
                *reinterpret_cast<const float4*>(gb0 + (size_t)row * HW + p4);
        }
    }
    __syncthreads();

    const float* fb = feat + (size_t)(b * V + vg * 4) * HW + c0 + pg * 4;

    float acc[4][4];
#pragma unroll
    for (int i = 0; i < 4; ++i)
#pragma unroll
        for (int j = 0; j < 4; ++j) acc[i][j] = 0.f;
    float s2a[4] = { 0.f, 0.f, 0.f, 0.f };

#pragma unroll
    for (int q = 0; q < 4; ++q) {
        int p = q * 32 + pg * 4;
        float4 g4[4], f4[4];
#pragma unroll
        for (int i = 0; i < 4; ++i)
            g4[i] = *reinterpret_cast<const float4*>(&g_lds[ng * 4 + i][p]);
#pragma unroll
        for (int j = 0; j < 4; ++j)
            f4[j] = *reinterpret_cast<const float4*>(fb + (size_t)j * HW + q * 32);
        float ffx = 0.f, ffy = 0.f, ffz = 0.f, ffw = 0.f;
#pragma unroll
        for (int j = 0; j < 4; ++j) {
            ffx = fmaf(f4[j].x, f4[j].x, ffx);
            ffy = fmaf(f4[j].y, f4[j].y, ffy);
            ffz = fmaf(f4[j].z, f4[j].z, ffz);
            ffw = fmaf(f4[j].w, f4[j].w, ffw);
        }
#pragma unroll
        for (int i = 0; i < 4; ++i) {
#pragma unroll
            for (int j = 0; j < 4; ++j) {
                acc[i][j] = fmaf(g4[i].x, f4[j].x, acc[i][j]);
                acc[i][j] = fmaf(g4[i].y, f4[j].y, acc[i][j]);
                acc[i][j] = fmaf(g4[i].z, f4[j].z, acc[i][j]);
                acc[i][j] = fmaf(g4[i].w, f4[j].w, acc[i][j]);
            }
            s2a[i] = fmaf(g4[i].x, ffx, s2a[i]);
            s2a[i] = fmaf(g4[i].y, ffy, s2a[i]);
            s2a[i] = fmaf(g4[i].z, ffz, s2a[i]);
            s2a[i] = fmaf(g4[i].w, ffw, s2a[i]);
        }
    }
#pragma unroll
    for (int m = 1; m <= 4; m <<= 1)
#pragma unroll
        for (int i = 0; i < 4; ++i)
#pragma unroll
            for (int j = 0; j < 4; ++j) acc[i][j] += __shfl_xor(acc[i][j], m);
    size_t blk = (size_t)(b * NCA + ch);
    if (pg == 0) {
        float* dst = ms_part + blk * 512;
#pragma unroll
        for (int i = 0; i < 4; ++i)
#pragma unroll
            for (int j = 0; j < 4; ++j)
                dst[(ng * 4 + i) * 32 + vg * 4 + j] = acc[i][j];
    }
#pragma unroll
    for (int m = 1; m <= 32; m <<= 1)
#pragma unroll
        for (int i = 0; i < 4; ++i) s2a[i] += __shfl_xor(s2a[i], m);
    if ((tid & 63) == 0) {
#pragma unroll
        for (int i = 0; i < 4; ++i)
            s2_part[blk * 16 + ng * 4 + i] = s2a[i];
    }
}

// ---------------- kAT: kA chunks (0..799) + kTop slabs (800..1119) ----------------
__global__ __launch_bounds__(256) void kAT(
    const float* __restrict__ pred, const float* __restrict__ feat,
    const float* __restrict__ gt,
    float* __restrict__ ms_part, float* __restrict__ s2_part,
    float* __restrict__ cand_val, int* __restrict__ cand_idx,
    float* __restrict__ cnt_part, float* __restrict__ out) {
    __shared__ float g_lds[16][132];
    __shared__ float rwv[4]; __shared__ int rwi[4]; __shared__ float csum[4];
    int s = blockIdx.x;
    int tid = threadIdx.x;
    if (s == 0 && tid == 0) { out[0] = 0.f; out[1] = 0.f; out[2] = 0.f; }
    if (s < 800) kA_body(s, tid, feat, gt, ms_part, s2_part, g_lds);
    else kTop_body(s - 800, tid, pred, gt, cand_val, cand_idx, cnt_part,
                   rwv, rwi, csum);
}

// ---------------- kB: block-wide reduces + 35-candidate merge + mu/E/l2 ----------------
__global__ __launch_bounds__(256) void kB(
    const float* __restrict__ feat, const float* __restrict__ ms_part,
    const float* __restrict__ s2_part,
    const float* __restrict__ cand_val, const int* __restrict__ cand_idx,
    const float* __restrict__ cnt_part, const int* __restrict__ valid,
    float* __restrict__ Ebuf, float* __restrict__ cntbuf, float* __restrict__ out) {
    int bn = blockIdx.x;
    int b = bn >> 4, n = bn & 15;
    int tid = threadIdx.x;
    int lane = tid & 63, wave = tid >> 6;

    __shared__ float msl[8][33];
    __shared__ float s2w[4];
    __shared__ int idx7[TOPK];

    {
        int sl = tid >> 5, v = tid & 31;
        const float* src = ms_part + ((size_t)(b * NCA) + sl) * 512 + n * 32 + v;
        float sm = 0.f;
#pragma unroll 5
        for (int k = 0; k < 25; ++k) sm += src[(size_t)(8 * k) * 512];
        msl[sl][v] = sm;
    }
    {
        float s2v = 0.f;
        if (tid < NCA) s2v = s2_part[((size_t)(b * NCA) + tid) * 16 + n];
#pragma unroll
        for (int m = 1; m <= 32; m <<= 1) s2v += __shfl_xor(s2v, m);
        if (lane == 0) s2w[wave] = s2v;
    }
    if (wave == 0) {
        float cv = -INFINITY; int ci = 0x7fffffff;
        if (lane < NSLB * TOPK) {
            cv = cand_val[(size_t)bn * NSLB * TOPK + lane];
            ci = cand_idx[(size_t)bn * NSLB * TOPK + lane];
        }
#pragma unroll
        for (int r = 0; r < TOPK; ++r) {
            float bv = cv; int bi = ci;
#pragma unroll
            for (int m = 1; m <= 32; m <<= 1) {
                float ov = __shfl_xor(bv, m);
                int oi = __shfl_xor(bi, m);
                if (better(ov, oi, bv, bi)) { bv = ov; bi = oi; }
            }
            if (ci == bi) { cv = -INFINITY; ci = 0x7fffffff; }
            if (lane == 0) idx7[r] = bi;
        }
    }
    __syncthreads();

    if (tid < 32) {
        const float* cp = cnt_part + bn * NSLB;
        float cnt = cp[0] + cp[1] + cp[2] + cp[3] + cp[4];
        float msum = msl[0][tid] + msl[1][tid] + msl[2][tid] + msl[3][tid]
                   + msl[4][tid] + msl[5][tid] + msl[6][tid] + msl[7][tid];
        float pix = fmaxf(cnt, 1.0f);
        float mu = msum / pix;
        Ebuf[(size_t)bn * 256 + tid] = mu;
        float msq = mu * mu;
#pragma unroll
        for (int m = 1; m <= 16; m <<= 1) msq += __shfl_xor(msq, m);
        if (tid == 0) {
            cntbuf[bn] = cnt;
            float s2 = s2w[0] + s2w[1] + s2w[2] + s2w[3];
            atomicAdd(out + 2, (s2 / pix - msq) * (float)valid[bn]);
        }
    } else {
        int t = tid - 32;
        if (t < 224) {
            int r = t >> 5, v = t & 31;
            Ebuf[(size_t)bn * 256 + (r + 1) * 32 + v] =
                feat[((size_t)b * V + v) * HW + idx7[r]];
        }
    }
}

// ---------------- kC: sigmoid-GEMM dice partials per (b, 64px chunk), LDS-staged feat ----------------
__global__ __launch_bounds__(256) void kC(
    const float* __restrict__ feat, const float* __restrict__ gt,
    const float* __restrict__ Ebuf, float* __restrict__ sums_part) {
    int s = blockIdx.x;                 // 1600
    int xcd = s & 7;
    int b = xcd >> 1;
    int ch = (s >> 3) * 2 + (xcd & 1);  // 0..399
    int c0 = ch * 64;
    int tid = threadIdx.x;
    int n = tid >> 4, pg = tid & 15;

    __shared__ __attribute__((aligned(16))) float f_lds[32][64];
    __shared__ float e_lds[8 * 16 * 36];
    __shared__ float red[16][17];

    const float* eb = Ebuf + (size_t)b * 4096;
#pragma unroll
    for (int k = 0; k < 4; ++k) {
        int q = (tid + 256 * k) * 4;
        int nn = q >> 8, rr = (q >> 5) & 7, vv = q & 31;
        *reinterpret_cast<float4*>(&e_lds[(rr * 16 + nn) * 36 + vv]) =
            *reinterpret_cast<const float4*>(eb + q);
    }
    {
        const float* fb0 = feat + (size_t)b * V * HW + c0;
#pragma unroll
        for (int k = 0; k < 2; ++k) {
            int u = tid + 256 * k;
            int v = u >> 4, p4 = (u & 15) * 4;
            *reinterpret_cast<float4*>(&f_lds[v][p4]) =
                *reinterpret_cast<const float4*>(fb0 + (size_t)v * HW + p4);
        }
    }
    __syncthreads();

    float4 g4 = *reinterpret_cast<const float4*>(gt + (size_t)(b * N + n) * HW + c0 + pg * 4);

    float acc[8][4];
#pragma unroll
    for (int r = 0; r < 8; ++r)
#pragma unroll
        for (int j = 0; j < 4; ++j) acc[r][j] = 0.f;

#pragma unroll
    for (int vq = 0; vq < 8; ++vq) {
        float4 f0 = *reinterpret_cast<const float4*>(&f_lds[vq * 4 + 0][pg * 4]);
        float4 f1 = *reinterpret_cast<const float4*>(&f_lds[vq * 4 + 1][pg * 4]);
        float4 f2 = *reinterpret_cast<const float4*>(&f_lds[vq * 4 + 2][pg * 4]);
        float4 f3 = *reinterpret_cast<const float4*>(&f_lds[vq * 4 + 3][pg * 4]);
#pragma unroll
        for (int r = 0; r < 8; ++r) {
            float4 e4 = *reinterpret_cast<const float4*>(&e_lds[(r * 16 + n) * 36 + vq * 4]);
            acc[r][0] = fmaf(e4.x, f0.x, acc[r][0]);
            acc[r][0] = fmaf(e4.y, f1.x, acc[r][0]);
            acc[r][0] = fmaf(e4.z, f2.x, acc[r][0]);
            acc[r][0] = fmaf(e4.w, f3.x, acc[r][0]);
            acc[r][1] = fmaf(e4.x, f0.y, acc[r][1]);
            acc[r][1] = fmaf(e4.y, f1.y, acc[r][1]);
            acc[r][1] = fmaf(e4.z, f2.y, acc[r][1]);
            acc[r][1] = fmaf(e4.w, f3.y, acc[r][1]);
            acc[r][2] = fmaf(e4.x, f0.z, acc[r][2]);
            acc[r][2] = fmaf(e4.y, f1.z, acc[r][2]);
            acc[r][2] = fmaf(e4.z, f2.z, acc[r][2]);
            acc[r][2] = fmaf(e4.w, f3.z, acc[r][2]);
            acc[r][3] = fmaf(e4.x, f0.w, acc[r][3]);
            acc[r][3] = fmaf(e4.y, f1.w, acc[r][3]);
            acc[r][3] = fmaf(e4.z, f2.w, acc[r][3]);
            acc[r][3] = fmaf(e4.w, f3.w, acc[r][3]);
        }
    }

    float p2[8], tp[8];
#pragma unroll
    for (int r = 0; r < 8; ++r) { p2[r] = 0.f; tp[r] = 0.f; }
    float ga[4] = { g4.x, g4.y, g4.z, g4.w };
#pragma unroll
    for (int r = 0; r < 8; ++r)
#pragma unroll
        for (int j = 0; j < 4; ++j) {
            float sg = 1.f / (1.f + __expf(-acc[r][j]));
            p2[r] = fmaf(sg, sg, p2[r]);
            tp[r] = fmaf(ga[j], sg, tp[r]);
        }
#pragma unroll
    for (int m = 1; m <= 8; m <<= 1)
#pragma unroll
        for (int r = 0; r < 8; ++r) {
            p2[r] += __shfl_xor(p2[r], m);
            tp[r] += __shfl_xor(tp[r], m);
        }
    if (pg == 0) {
#pragma unroll
        for (int r = 0; r < 8; ++r) {
            red[n][r * 2] = p2[r];
            red[n][r * 2 + 1] = tp[r];
        }
    }
    __syncthreads();
    sums_part[(size_t)(b * NCC + ch) * 256 + tid] = red[tid >> 4][tid & 15];
}

// ---------------- kD: reduce dice partials (400 chunks), fold dice losses ----------------
__global__ __launch_bounds__(256) void kD(
    const float* __restrict__ sums_part, const float* __restrict__ cntbuf,
    const int* __restrict__ valid, float* __restrict__ out) {
    int bn = blockIdx.x;       // 64
    int b = bn >> 4, n = bn & 15;
    int tid = threadIdx.x;
    int slot = tid & 15, cg = tid >> 4;
    int lane = tid & 63, wave = tid >> 6;

    __shared__ float red2[4][17];
    __shared__ float fin[16];

    float sv = 0.f;
    const float* src = sums_part + (size_t)b * NCC * 256 + n * 16 + slot;
    for (int k = 0; k < 25; ++k) sv += src[(size_t)(cg + 16 * k) * 256];
    sv += __shfl_xor(sv, 16);
    sv += __shfl_xor(sv, 32);
    if (lane < 16) red2[wave][lane] = sv;
    __syncthreads();
    if (tid < 16) fin[tid] = red2[0][tid] + red2[1][tid] + red2[2][tid] + red2[3][tid];
    __syncthreads();

    if (tid == 0) {
        float vw = (float)valid[bn];
        float cnt = cntbuf[bn];
        float mloss = 0.f, iloss = 0.f;
#pragma unroll
        for (int r = 0; r < 8; ++r) {
            float p2 = fin[r * 2];
            float tp = fin[r * 2 + 1];
            float denom = fmaxf(p2 + cnt, 1e-8f);
            float dice = 1.f - 2.f * tp / denom;
            if (r == 0) mloss = dice * vw;
            else iloss += dice * vw;
        }
        atomicAdd(out + 0, mloss);
        atomicAdd(out + 1, iloss);
    }
}

extern "C" void kernel_launch(void* const* d_in, const int* in_sizes, int n_in,
                              void* d_out, int out_size, void* d_ws, size_t ws_size,
                              hipStream_t stream) {
    const float* pred = (const float*)d_in[0];
    const float* feat = (const float*)d_in[1];
    const float* gtin = (const float*)d_in[2];
    const int* valid  = (const int*)d_in[3];
    float* out = (float*)d_out;

    char* ws = (char*)d_ws;
    float* ms_part   = (float*)(ws);                 // 800*512*4   = 1,638,400
    float* s2_part   = (float*)(ws + 1638400);       // 800*16*4    =    51,200
    float* cand_val  = (float*)(ws + 1689600);       // 320*7*4     =     8,960
    int*   cand_idx  = (int*)  (ws + 1698560);       //                   8,960
    float* cnt_part  = (float*)(ws + 1707520);       // 320*4       =     1,280
    float* sums_part = (float*)(ws + 1708800);       // 1600*256*4  = 1,638,400
    float* Ebuf      = (float*)(ws + 3347200);       // 64*256*4    =    65,536
    float* cntbuf    = (float*)(ws + 3412736);       // 256

    kAT<<<800 + B * N * NSLB, 256, 0, stream>>>(pred, feat, gtin, ms_part, s2_part,
                                                cand_val, cand_idx, cnt_part, out);
    kB<<<B * N, 256, 0, stream>>>(feat, ms_part, s2_part, cand_val, cand_idx,
                                  cnt_part, valid, Ebuf, cntbuf, out);
    kC<<<B * NCC, 256, 0, stream>>>(feat, gtin, Ebuf, sums_part);
    kD<<<B * N, 256, 0, stream>>>(sums_part, cntbuf, valid, out);
}